// Round 1
// baseline (1480.285 us; speedup 1.0000x reference)
//
#include <hip/hip_runtime.h>

#define H    51
#define BB   2048
#define TSEQ 1024
#define NB   8
#define NT   1024       // 16 waves, 4/SIMD
#define KP   72         // bf16 h-row stride (144B, 16B-aligned)

typedef __attribute__((ext_vector_type(8))) short short8;
typedef __attribute__((ext_vector_type(4))) float f32x4;

__device__ __forceinline__ float sigm(float x) { return 1.0f / (1.0f + __expf(-x)); }
__device__ __forceinline__ float tanh_(float x) { return 1.0f - 2.0f / (__expf(2.0f * x) + 1.0f); }
__device__ __forceinline__ unsigned short f2bf(float f) {
    unsigned u = __float_as_uint(f);
    return (unsigned short)((u + 0x7fffu + ((u >> 16) & 1u)) >> 16);   // RNE
}
__device__ __forceinline__ float bf2f(unsigned short s) { return __uint_as_float(((unsigned)s) << 16); }

// single-instruction RNE f32->bf16 (low half of v_cvt_pk_bf16_f32)
__device__ __forceinline__ short f2bf_rn(float f) {
    unsigned r;
    asm("v_cvt_pk_bf16_f32 %0, %1, %2" : "=v"(r) : "v"(f), "v"(f));
    return (short)r;
}

#define MFMA(a, b, c) __builtin_amdgcn_mfma_f32_16x16x32_bf16((a), (b), (c), 0, 0, 0)

// lgkmcnt-only barrier: LDS producer/consumer ordering WITHOUT draining vmcnt.
// __syncthreads() forces s_waitcnt vmcnt(0), putting wave14's global-store ack
// (every step) and wave13's global-load latency (every 4th) on the barrier path.
#define BARR() do { asm volatile("s_waitcnt lgkmcnt(0)" ::: "memory");            \
                    __builtin_amdgcn_s_barrier(); } while (0)

struct SM {
    alignas(16) short h1[2][8][KP];      // parity-buffered h1 (bf16); rows = real batches only
    alignas(16) short h2[2][8][KP];      // (lanes n>=8 re-read row n-8: broadcast, no conflict)
    alignas(16) float part[2][14][4][8]; // out partials [parity][tile 13+pad][q][batch]
    alignas(16) float xstep[2][8][4];    // parity-chunked x staging [buf][batch][slot]
    float olds[8];
};

// A-frags (hi/lo split) for tile T of gate-stacked [3H][H] matrix, 4-padded rows:
// padded row 16T+n -> element j=4T+(n>>2), gate c=n&3 (c==3 or j>=H: zero row)
__device__ __forceinline__ void loadA(const float* __restrict__ src, int T, int n, int q,
                                      short8* ah, short8* al) {
    const int jt = 4 * T + (n >> 2);
    const int c  = n & 3;
    const bool rv = (c < 3) && (jt < H);
#pragma unroll
    for (int kb = 0; kb < 2; ++kb) {
        short8 hi, lo;
#pragma unroll
        for (int jj = 0; jj < 8; ++jj) {
            const int k = kb * 32 + q * 8 + jj;
            const float v = (rv && k < H) ? src[(c * H + jt) * H + k] : 0.f;
            const unsigned short hb = f2bf(v);
            hi[jj] = (short)hb;
            lo[jj] = (short)f2bf(v - bf2f(hb));
        }
        ah[kb] = hi; al[kb] = lo;
    }
}

// 2x2 split matvec: two independent 2-MFMA chains, merged with one vector add.
// Halves the dependent-MFMA depth vs the chained 4-MFMA dot4.
__device__ __forceinline__ f32x4 dot22(const short8* ah, const short8* al,
                                       short8 b0, short8 b1, f32x4 init) {
    f32x4 p = MFMA(al[0], b0, init);
    p = MFMA(ah[0], b0, p);
    f32x4 z = {0.f, 0.f, 0.f, 0.f};
    f32x4 r = MFMA(al[1], b1, z);
    r = MFMA(ah[1], b1, r);
    return p + r;
}

__global__ __launch_bounds__(NT, 1) void gru_persist(
    const float* __restrict__ inp, const int* __restrict__ fut,
    const float* __restrict__ wih1, const float* __restrict__ whh1,
    const float* __restrict__ bih1, const float* __restrict__ bhh1,
    const float* __restrict__ wih2, const float* __restrict__ whh2,
    const float* __restrict__ bih2, const float* __restrict__ bhh2,
    const float* __restrict__ wlin, const float* __restrict__ blin,
    float* __restrict__ out)
{
    __shared__ SM sm;
    const int t = threadIdx.x, bg = blockIdx.x;
    const int w = t >> 6, lane = t & 63;
    const int n = lane & 15, q = lane >> 4;
    const bool doM = (w < 13);                 // matvec waves: one tile triple each
    const int  T   = doM ? w : 0;
    const int  j   = 4 * T + q;
    const bool jv  = doM && (j < H) && (n < NB);
    const int  jcl = (j < H) ? j : 0;

    // ---- A-fragments: 12 short8 = 48 VGPRs ----
    short8 a1h[2], a1l[2], a2h[2], a2l[2], a3h[2], a3l[2];
    loadA(whh1, T, n, q, a1h, a1l);
    loadA(whh2, T, n, q, a2h, a2l);
    loadA(wih2, T, n, q, a3h, a3l);

    // ---- per-lane constants; biases as f32x4 accumulator inits ----
    const f32x4 b1v = {bhh1[jcl], bhh1[H + jcl], bhh1[2 * H + jcl], 0.f};
    const f32x4 b2v = {bhh2[jcl], bhh2[H + jcl], bhh2[2 * H + jcl], 0.f};
    const f32x4 c2v = {bih2[jcl], bih2[H + jcl], bih2[2 * H + jcl], 0.f};
    const float w1r = wih1[jcl], w1z = wih1[H + jcl], w1n = wih1[2 * H + jcl];
    const float c1r = bih1[jcl], c1z = bih1[H + jcl], c1n = bih1[2 * H + jcl];
    const float wl  = wlin[jcl];
    const float blin_r = blin[0];

    // ---- LDS init ----
    for (int i = t; i < 2 * 8 * KP; i += NT) { ((short*)sm.h1)[i] = 0; ((short*)sm.h2)[i] = 0; }
    for (int i = t; i < 2 * 14 * 4 * 8; i += NT) ((float*)sm.part)[i] = 0.f;
    if (t < 8) sm.olds[t] = 0.f;

    // ---- x staging: wave 13, lanes 0..7; parity-chunked double buffer ----
    const bool doX = (w == 13) && (lane < 8);
    const int  bs  = lane;
    const float* xrow = inp + (size_t)(bg * NB + (doX ? bs : 0)) * TSEQ;
    float4 xnxt = make_float4(0.f, 0.f, 0.f, 0.f);
    if (doX) {
        *(float4*)&sm.xstep[0][bs][0] = *(const float4*)xrow;     // x[0..3]
        xnxt = *(const float4*)(xrow + 4);                        // x[4..7]
    }

    float h1o = 0.f, h2o = 0.f;     // per-lane f32 hidden (element j, batch n)
    const int TT = TSEQ + fut[0];
    float* outp = out + (size_t)(bg * NB) * (size_t)TT;
    __syncthreads();

// wave-14 full output reduction: 52 tile-q partials per batch, conflict-free reads
#define RED14(PBUF, TIDX, SAVEO)                                                  \
{                                                                                 \
    const float* pb = &sm.part[PBUF][0][0][0];                                    \
    float v = 0.f;                                                                \
    _Pragma("unroll")                                                             \
    for (int c = 0; c < 7; ++c) v += pb[64 * c + lane];                           \
    v += __shfl_xor(v, 8);                                                        \
    v += __shfl_xor(v, 16);                                                       \
    v += __shfl_xor(v, 32);                                                       \
    if (lane < 8) {                                                               \
        const float o_ = v + blin_r;                                              \
        if (SAVEO) sm.olds[lane] = o_;                                            \
        outp[(size_t)lane * TT + (TIDX)] = o_;                                    \
    }                                                                             \
}

#define STEP(IV, PAR, DOL2, DORED)                                                \
{                                                                                 \
    const int i_ = (IV);                                                          \
    if (doM) {                                                                    \
        const short8 b10 = *(const short8*)&sm.h1[PAR][n & 7][q * 8];             \
        const short8 b11 = *(const short8*)&sm.h1[PAR][n & 7][32 + q * 8];        \
        if (DOL2) {                                                               \
            const short8 b20 = *(const short8*)&sm.h2[PAR][n & 7][q * 8];         \
            const short8 b21 = *(const short8*)&sm.h2[PAR][n & 7][32 + q * 8];    \
            const f32x4 g  = dot22(a2h, a2l, b20, b21, b2v);                      \
            const f32x4 gi = dot22(a3h, a3l, b10, b11, c2v);                      \
            const float gr = sigm(gi.x + g.x);                                    \
            const float gz = sigm(gi.y + g.y);                                    \
            const float gn = tanh_(fmaf(gr, g.z, gi.z));                          \
            const float hn = gn + gz * (h2o - gn);                                \
            h2o = hn;                                                             \
            if (jv) { sm.h2[(PAR) ^ 1][n][j] = f2bf_rn(hn);                       \
                      sm.part[PAR][T][q][n] = wl * hn; }                          \
        }                                                                         \
        {                                                                         \
            const float xv = sm.xstep[(i_ >> 2) & 1][n & 7][i_ & 3];              \
            const f32x4 a = dot22(a1h, a1l, b10, b11, b1v);                       \
            const float gr = sigm(fmaf(xv, w1r, c1r) + a.x);                      \
            const float gz = sigm(fmaf(xv, w1z, c1z) + a.y);                      \
            const float gn = tanh_(fmaf(gr, a.z, fmaf(xv, w1n, c1n)));            \
            const float hn = gn + gz * (h1o - gn);                                \
            h1o = hn;                                                             \
            if (jv) sm.h1[(PAR) ^ 1][n][j] = f2bf_rn(hn);                         \
        }                                                                         \
    } else if (w == 14) {                                                         \
        if (DORED) RED14((PAR) ^ 1, i_ - 2, false)                                \
    } else if (doX && (i_ & 3) == 3 && (i_ + 1) < TSEQ) {                         \
        *(float4*)&sm.xstep[((i_ + 1) >> 2) & 1][bs][0] = xnxt;                   \
        if (i_ + 8 < TSEQ) xnxt = *(const float4*)(xrow + i_ + 5);                \
    }                                                                             \
    BARR();                                                                       \
}

    // ========== MAIN LOOP: 1 barrier/step, parity-specialized unroll-2 ==========
    STEP(0, 0, false, false)
    STEP(1, 1, true,  false)
    for (int i = 2; i < TSEQ; i += 2) {
        STEP(i,     0, true, true)
        STEP(i + 1, 1, true, true)
    }

    // ========== EPILOGUE: h2(TSEQ-1), flush o(TSEQ-2) and o(TSEQ-1) ==========
    // state: h1(TSEQ-1) in h1[0], h2(TSEQ-2) in h2[0]; part[1] holds o(TSEQ-2) partials
    if (doM) {
        const short8 b10 = *(const short8*)&sm.h1[0][n & 7][q * 8];
        const short8 b11 = *(const short8*)&sm.h1[0][n & 7][32 + q * 8];
        const short8 b20 = *(const short8*)&sm.h2[0][n & 7][q * 8];
        const short8 b21 = *(const short8*)&sm.h2[0][n & 7][32 + q * 8];
        const f32x4 g  = dot22(a2h, a2l, b20, b21, b2v);
        const f32x4 gi = dot22(a3h, a3l, b10, b11, c2v);
        const float gr = sigm(gi.x + g.x);
        const float gz = sigm(gi.y + g.y);
        const float gn = tanh_(fmaf(gr, g.z, gi.z));
        const float hn = gn + gz * (h2o - gn);
        h2o = hn;
        if (jv) { sm.h2[1][n][j] = f2bf_rn(hn); sm.part[0][T][q][n] = wl * hn; }
    } else if (w == 14) {
        RED14(1, TSEQ - 2, false)
    }
    BARR();
    if (w == 14) {
        RED14(0, TSEQ - 1, true)
    }
    BARR();

    // ========== FUTURE LOOP: serial feedback, 3 barriers/step ==========
    int fp1 = 0, fh2 = 1;    // h1(TSEQ-1) in h1[0], h2(TSEQ-1) in h2[1]
    for (int ts = TSEQ; ts < TT; ++ts) {
        float g2r, g2z, g2n;
        if (doM) {
            const short8 b10 = *(const short8*)&sm.h1[fp1][n & 7][q * 8];
            const short8 b11 = *(const short8*)&sm.h1[fp1][n & 7][32 + q * 8];
            const short8 b20 = *(const short8*)&sm.h2[fh2][n & 7][q * 8];
            const short8 b21 = *(const short8*)&sm.h2[fh2][n & 7][32 + q * 8];
            const float  xv  = sm.olds[n & 7];
            {
                const f32x4 g = dot22(a2h, a2l, b20, b21, b2v);
                g2r = g.x; g2z = g.y; g2n = g.z;
            }
            {
                const f32x4 a = dot22(a1h, a1l, b10, b11, b1v);
                const float gr = sigm(fmaf(xv, w1r, c1r) + a.x);
                const float gz = sigm(fmaf(xv, w1z, c1z) + a.y);
                const float gn = tanh_(fmaf(gr, a.z, fmaf(xv, w1n, c1n)));
                const float hn = gn + gz * (h1o - gn);
                h1o = hn;
                if (jv) sm.h1[fp1 ^ 1][n][j] = f2bf_rn(hn);
            }
        }
        BARR();
        if (doM) {
            const short8 c0 = *(const short8*)&sm.h1[fp1 ^ 1][n & 7][q * 8];
            const short8 c1 = *(const short8*)&sm.h1[fp1 ^ 1][n & 7][32 + q * 8];
            const f32x4 gi = dot22(a3h, a3l, c0, c1, c2v);
            const float gr = sigm(gi.x + g2r);
            const float gz = sigm(gi.y + g2z);
            const float gn = tanh_(fmaf(gr, g2n, gi.z));
            const float hn = gn + gz * (h2o - gn);
            h2o = hn;
            if (jv) { sm.h2[fh2 ^ 1][n][j] = f2bf_rn(hn); sm.part[0][T][q][n] = wl * hn; }
        }
        BARR();
        if (w == 14) {
            RED14(0, ts, true)
        }
        BARR();
        fp1 ^= 1; fh2 ^= 1;
    }
}

extern "C" void kernel_launch(void* const* d_in, const int* in_sizes, int n_in,
                              void* d_out, int out_size, void* d_ws, size_t ws_size,
                              hipStream_t stream) {
    (void)in_sizes; (void)n_in; (void)d_ws; (void)ws_size; (void)out_size;
    gru_persist<<<BB / NB, NT, 0, stream>>>(
        (const float*)d_in[0], (const int*)d_in[1],
        (const float*)d_in[2], (const float*)d_in[3], (const float*)d_in[4], (const float*)d_in[5],
        (const float*)d_in[6], (const float*)d_in[7], (const float*)d_in[8], (const float*)d_in[9],
        (const float*)d_in[10], (const float*)d_in[11],
        (float*)d_out);
}

// Round 3
// 1016.262 us; speedup vs baseline: 1.4566x; 1.4566x over previous
//
#include <hip/hip_runtime.h>

#define H    51
#define G    153
#define BB   2048
#define TSEQ 1024
#define NB   8
#define NT   1024       // 16 waves, 4/SIMD
#define KP   72         // bf16 h-row stride (144B, 16B-aligned)

typedef __attribute__((ext_vector_type(8))) short short8;
typedef __attribute__((ext_vector_type(4))) float f32x4;

// v_rcp_f32 (1 ulp) via compiler-known intrinsic — replaces hipcc's ~10-op
// IEEE division sequence; hazard/wait-state handling stays with the compiler.
__device__ __forceinline__ float rcp_(float x) { return __builtin_amdgcn_rcpf(x); }

__device__ __forceinline__ float sigm(float x) { return rcp_(1.0f + __expf(-x)); }
__device__ __forceinline__ float tanh_(float x) { return fmaf(-2.0f, rcp_(__expf(2.0f * x) + 1.0f), 1.0f); }

__device__ __forceinline__ unsigned short f2bf(float f) {
    unsigned u = __float_as_uint(f);
    return (unsigned short)((u + 0x7fffu + ((u >> 16) & 1u)) >> 16);   // RNE
}
__device__ __forceinline__ float bf2f(unsigned short s) { return __uint_as_float(((unsigned)s) << 16); }

// single-instruction RNE f32->bf16 (low half of v_cvt_pk_bf16_f32); proven r1
__device__ __forceinline__ short f2bf_rn(float f) {
    unsigned r;
    asm("v_cvt_pk_bf16_f32 %0, %1, %2" : "=v"(r) : "v"(f), "v"(f));
    return (short)r;
}

#define MFMA(a, b, c) __builtin_amdgcn_mfma_f32_16x16x32_bf16((a), (b), (c), 0, 0, 0)

// lgkmcnt-only barrier: LDS producer/consumer ordering WITHOUT draining vmcnt,
// keeping wave14's store-acks and wave13's prefetch loads off the barrier path.
// (h-state is LDS-only; out-stores are never read back; x-prefetch is
// register-private with compiler-inserted vmcnt before use.)
#define BARR() do { asm volatile("s_waitcnt lgkmcnt(0)" ::: "memory");            \
                    __builtin_amdgcn_s_barrier(); } while (0)

struct SM {
    alignas(16) short h1[2][16][KP];    // parity-buffered h1 (bf16), [n][k]
    alignas(16) short h2[2][16][KP];    // parity-buffered h2
    alignas(16) float part[2][16][8];   // out partials [parity][tile][batch]
    alignas(16) float xstep[2][8][4];   // parity-chunked x staging [buf][batch][slot]
    float olds[8];
};

// A-frags (hi/lo split) for tile T of gate-stacked [3H][H] matrix, 4-padded rows:
// padded row 16T+n -> element j=4T+(n>>2), gate c=n&3 (c==3 or j>=H: zero row)
__device__ __forceinline__ void loadA(const float* __restrict__ src, int T, int n, int q,
                                      short8* ah, short8* al) {
    const int jt = 4 * T + (n >> 2);
    const int c  = n & 3;
    const bool rv = (c < 3) && (jt < H);
#pragma unroll
    for (int kb = 0; kb < 2; ++kb) {
        short8 hi, lo;
#pragma unroll
        for (int jj = 0; jj < 8; ++jj) {
            const int k = kb * 32 + q * 8 + jj;
            const float v = (rv && k < H) ? src[(c * H + jt) * H + k] : 0.f;
            const unsigned short hb = f2bf(v);
            hi[jj] = (short)hb;
            lo[jj] = (short)f2bf(v - bf2f(hb));
        }
        ah[kb] = hi; al[kb] = lo;
    }
}

// chained 4-MFMA 2-term split matvec, bias folded into accumulator init
__device__ __forceinline__ f32x4 dot4(const short8* ah, const short8* al,
                                      short8 b0, short8 b1, f32x4 init) {
    f32x4 acc = init;
    acc = MFMA(al[0], b0, acc);
    acc = MFMA(al[1], b1, acc);
    acc = MFMA(ah[0], b0, acc);
    acc = MFMA(ah[1], b1, acc);
    return acc;
}

__global__ __launch_bounds__(NT, 1) void gru_persist(
    const float* __restrict__ inp, const int* __restrict__ fut,
    const float* __restrict__ wih1, const float* __restrict__ whh1,
    const float* __restrict__ bih1, const float* __restrict__ bhh1,
    const float* __restrict__ wih2, const float* __restrict__ whh2,
    const float* __restrict__ bih2, const float* __restrict__ bhh2,
    const float* __restrict__ wlin, const float* __restrict__ blin,
    float* __restrict__ out)
{
    __shared__ SM sm;
    const int t = threadIdx.x, bg = blockIdx.x;
    const int w = t >> 6, lane = t & 63;
    const int n = lane & 15, q = lane >> 4;
    const bool doM = (w < 13);                 // matvec waves: one tile triple each
    const int  T   = doM ? w : 0;
    const int  j   = 4 * T + q;
    const bool jv  = doM && (j < H) && (n < NB);
    const int  jcl = (j < H) ? j : 0;

    // ---- A-fragments: 12 short8 = 48 VGPRs ----
    short8 a1h[2], a1l[2], a2h[2], a2l[2], a3h[2], a3l[2];
    loadA(whh1, T, n, q, a1h, a1l);
    loadA(whh2, T, n, q, a2h, a2l);
    loadA(wih2, T, n, q, a3h, a3l);

    // ---- per-lane constants; biases as f32x4 accumulator inits ----
    const f32x4 b1v = {bhh1[jcl], bhh1[H + jcl], bhh1[2 * H + jcl], 0.f};
    const f32x4 b2v = {bhh2[jcl], bhh2[H + jcl], bhh2[2 * H + jcl], 0.f};
    const f32x4 c2v = {bih2[jcl], bih2[H + jcl], bih2[2 * H + jcl], 0.f};
    const float w1r = wih1[jcl], w1z = wih1[H + jcl], w1n = wih1[2 * H + jcl];
    const float c1r = bih1[jcl], c1z = bih1[H + jcl], c1n = bih1[2 * H + jcl];
    const float wl  = wlin[jcl];
    const float blin_r = blin[0];

    // ---- LDS init ----
    for (int i = t; i < 2 * 16 * KP; i += NT) { ((short*)sm.h1)[i] = 0; ((short*)sm.h2)[i] = 0; }
    if (t < 256) ((float*)sm.part)[t] = 0.f;
    if (t < 8) sm.olds[t] = 0.f;

    // ---- x staging: wave 13, lanes 0..7; parity-chunked double buffer ----
    const bool doX = (w == 13) && (lane < 8);
    const int  bs  = lane;
    const float* xrow = inp + (size_t)(bg * NB + (doX ? bs : 0)) * TSEQ;
    float4 xnxt = make_float4(0.f, 0.f, 0.f, 0.f);
    if (doX) {
        *(float4*)&sm.xstep[0][bs][0] = *(const float4*)xrow;     // x[0..3]
        xnxt = *(const float4*)(xrow + 4);                        // x[4..7]
    }

    float h1o = 0.f, h2o = 0.f;     // per-lane f32 hidden (element j, batch n)
    const int TT = TSEQ + fut[0];
    float* outp = out + (size_t)(bg * NB) * (size_t)TT;
    __syncthreads();

#define STEP(IV, PAR, DOL2, DORED)                                                \
{                                                                                 \
    const int i_ = (IV);                                                          \
    if (doM) {                                                                    \
        const short8 b10 = *(const short8*)&sm.h1[PAR][n][q * 8];                 \
        const short8 b11 = *(const short8*)&sm.h1[PAR][n][32 + q * 8];            \
        if (DOL2) {                                                               \
            const short8 b20 = *(const short8*)&sm.h2[PAR][n][q * 8];             \
            const short8 b21 = *(const short8*)&sm.h2[PAR][n][32 + q * 8];        \
            const f32x4 g  = dot4(a2h, a2l, b20, b21, b2v);                       \
            const f32x4 gi = dot4(a3h, a3l, b10, b11, c2v);                       \
            const float gr = sigm(gi.x + g.x);                                    \
            const float gz = sigm(gi.y + g.y);                                    \
            const float gn = tanh_(fmaf(gr, g.z, gi.z));                          \
            const float hn = gn + gz * (h2o - gn);                                \
            h2o = hn;                                                             \
            float pout = 0.f;                                                     \
            if (jv) { sm.h2[(PAR) ^ 1][n][j] = f2bf_rn(hn); pout = wl * hn; }     \
            pout += __shfl_xor(pout, 16);                                         \
            pout += __shfl_xor(pout, 32);                                         \
            if (q == 0 && n < NB) sm.part[PAR][T][n] = pout;                      \
        }                                                                         \
        {                                                                         \
            const float xv = sm.xstep[(i_ >> 2) & 1][n & 7][i_ & 3];              \
            const f32x4 a = dot4(a1h, a1l, b10, b11, b1v);                        \
            const float gr = sigm(fmaf(xv, w1r, c1r) + a.x);                      \
            const float gz = sigm(fmaf(xv, w1z, c1z) + a.y);                      \
            const float gn = tanh_(fmaf(gr, a.z, fmaf(xv, w1n, c1n)));            \
            const float hn = gn + gz * (h1o - gn);                                \
            h1o = hn;                                                             \
            if (jv) sm.h1[(PAR) ^ 1][n][j] = f2bf_rn(hn);                         \
        }                                                                         \
    } else if (w == 14) {                                                         \
        if (DORED) {                                                              \
            const float* pb = &sm.part[(PAR) ^ 1][0][0];                          \
            float v = pb[lane] + pb[64 + lane];                                   \
            v += __shfl_xor(v, 8);                                                \
            v += __shfl_xor(v, 16);                                               \
            v += __shfl_xor(v, 32);                                               \
            if (lane < 8) outp[(size_t)lane * TT + (i_ - 2)] = v + blin_r;        \
        }                                                                         \
    } else if (doX && (i_ & 3) == 3 && (i_ + 1) < TSEQ) {                         \
        *(float4*)&sm.xstep[((i_ + 1) >> 2) & 1][bs][0] = xnxt;                   \
        if (i_ + 8 < TSEQ) xnxt = *(const float4*)(xrow + i_ + 5);                \
    }                                                                             \
    BARR();                                                                       \
}

    // ========== MAIN LOOP: 1 barrier/step, parity-specialized unroll-2 ==========
    STEP(0, 0, false, false)
    STEP(1, 1, true,  false)
    for (int i = 2; i < TSEQ; i += 2) {
        STEP(i,     0, true, true)
        STEP(i + 1, 1, true, true)
    }

    // ========== EPILOGUE: h2(TSEQ-1), flush o(TSEQ-2) and o(TSEQ-1) ==========
    // state: h1(TSEQ-1) in h1[0], h2(TSEQ-2) in h2[0]; part[1] holds o(TSEQ-2) partials
    if (doM) {
        const short8 b10 = *(const short8*)&sm.h1[0][n][q * 8];
        const short8 b11 = *(const short8*)&sm.h1[0][n][32 + q * 8];
        const short8 b20 = *(const short8*)&sm.h2[0][n][q * 8];
        const short8 b21 = *(const short8*)&sm.h2[0][n][32 + q * 8];
        const f32x4 g  = dot4(a2h, a2l, b20, b21, b2v);
        const f32x4 gi = dot4(a3h, a3l, b10, b11, c2v);
        const float gr = sigm(gi.x + g.x);
        const float gz = sigm(gi.y + g.y);
        const float gn = tanh_(fmaf(gr, g.z, gi.z));
        const float hn = gn + gz * (h2o - gn);
        h2o = hn;
        float pout = 0.f;
        if (jv) { sm.h2[1][n][j] = f2bf_rn(hn); pout = wl * hn; }
        pout += __shfl_xor(pout, 16);
        pout += __shfl_xor(pout, 32);
        if (q == 0 && n < NB) sm.part[0][T][n] = pout;
    } else if (w == 14) {
        const float* pb = &sm.part[1][0][0];
        float v = pb[lane] + pb[64 + lane];
        v += __shfl_xor(v, 8);
        v += __shfl_xor(v, 16);
        v += __shfl_xor(v, 32);
        if (lane < 8) outp[(size_t)lane * TT + (TSEQ - 2)] = v + blin_r;
    }
    BARR();
    if (w == 14) {
        const float* pb = &sm.part[0][0][0];
        float v = pb[lane] + pb[64 + lane];
        v += __shfl_xor(v, 8);
        v += __shfl_xor(v, 16);
        v += __shfl_xor(v, 32);
        if (lane < 8) {
            const float o = v + blin_r;
            sm.olds[lane] = o;
            outp[(size_t)lane * TT + (TSEQ - 1)] = o;
        }
    }
    BARR();

    // ========== FUTURE LOOP: serial feedback, 3 barriers/step ==========
    int fp1 = 0, fh2 = 1;    // h1(TSEQ-1) in h1[0], h2(TSEQ-1) in h2[1]
    for (int ts = TSEQ; ts < TT; ++ts) {
        float g2r, g2z, g2n;
        if (doM) {
            const short8 b10 = *(const short8*)&sm.h1[fp1][n][q * 8];
            const short8 b11 = *(const short8*)&sm.h1[fp1][n][32 + q * 8];
            const short8 b20 = *(const short8*)&sm.h2[fh2][n][q * 8];
            const short8 b21 = *(const short8*)&sm.h2[fh2][n][32 + q * 8];
            const float  xv  = sm.olds[n & 7];
            {
                const f32x4 g = dot4(a2h, a2l, b20, b21, b2v);
                g2r = g.x; g2z = g.y; g2n = g.z;
            }
            {
                const f32x4 a = dot4(a1h, a1l, b10, b11, b1v);
                const float gr = sigm(fmaf(xv, w1r, c1r) + a.x);
                const float gz = sigm(fmaf(xv, w1z, c1z) + a.y);
                const float gn = tanh_(fmaf(gr, a.z, fmaf(xv, w1n, c1n)));
                const float hn = gn + gz * (h1o - gn);
                h1o = hn;
                if (jv) sm.h1[fp1 ^ 1][n][j] = f2bf_rn(hn);
            }
        }
        BARR();
        if (doM) {
            const short8 c0 = *(const short8*)&sm.h1[fp1 ^ 1][n][q * 8];
            const short8 c1 = *(const short8*)&sm.h1[fp1 ^ 1][n][32 + q * 8];
            const f32x4 gi = dot4(a3h, a3l, c0, c1, c2v);
            const float gr = sigm(gi.x + g2r);
            const float gz = sigm(gi.y + g2z);
            const float gn = tanh_(fmaf(gr, g2n, gi.z));
            const float hn = gn + gz * (h2o - gn);
            h2o = hn;
            float pout = 0.f;
            if (jv) { sm.h2[fh2 ^ 1][n][j] = f2bf_rn(hn); pout = wl * hn; }
            pout += __shfl_xor(pout, 16);
            pout += __shfl_xor(pout, 32);
            if (q == 0 && n < NB) sm.part[0][T][n] = pout;
        }
        BARR();
        if (w == 14) {
            const float* pb = &sm.part[0][0][0];
            float v = pb[lane] + pb[64 + lane];
            v += __shfl_xor(v, 8);
            v += __shfl_xor(v, 16);
            v += __shfl_xor(v, 32);
            if (lane < 8) {
                const float o = v + blin_r;
                sm.olds[lane] = o;
                outp[(size_t)lane * TT + ts] = o;
            }
        }
        BARR();
        fp1 ^= 1; fh2 ^= 1;
    }
}

extern "C" void kernel_launch(void* const* d_in, const int* in_sizes, int n_in,
                              void* d_out, int out_size, void* d_ws, size_t ws_size,
                              hipStream_t stream) {
    (void)in_sizes; (void)n_in; (void)d_ws; (void)ws_size; (void)out_size;
    gru_persist<<<BB / NB, NT, 0, stream>>>(
        (const float*)d_in[0], (const int*)d_in[1],
        (const float*)d_in[2], (const float*)d_in[3], (const float*)d_in[4], (const float*)d_in[5],
        (const float*)d_in[6], (const float*)d_in[7], (const float*)d_in[8], (const float*)d_in[9],
        (const float*)d_in[10], (const float*)d_in[11],
        (float*)d_out);
}

// Round 4
// 894.335 us; speedup vs baseline: 1.6552x; 1.1363x over previous
//
#include <hip/hip_runtime.h>

#define H    51
#define BB   2048
#define TSEQ 1024
#define NB   8
#define NT   1024       // 16 waves, 4/SIMD
#define KP   72         // bf16 h-row stride (144B, 16B-aligned)

typedef __attribute__((ext_vector_type(8))) short short8;
typedef __attribute__((ext_vector_type(4))) float f32x4;

// v_rcp_f32 (1 ulp) via compiler-known intrinsic (proven r3)
__device__ __forceinline__ float rcp_(float x) { return __builtin_amdgcn_rcpf(x); }

__device__ __forceinline__ float sigm(float x) { return rcp_(1.0f + __expf(-x)); }
__device__ __forceinline__ float tanh_(float x) { return fmaf(-2.0f, rcp_(__expf(2.0f * x) + 1.0f), 1.0f); }

__device__ __forceinline__ unsigned short f2bf(float f) {
    unsigned u = __float_as_uint(f);
    return (unsigned short)((u + 0x7fffu + ((u >> 16) & 1u)) >> 16);   // RNE
}
__device__ __forceinline__ float bf2f(unsigned short s) { return __uint_as_float(((unsigned)s) << 16); }

// single-instruction RNE f32->bf16 (low half of v_cvt_pk_bf16_f32); proven r1/r3
__device__ __forceinline__ short f2bf_rn(float f) {
    unsigned r;
    asm("v_cvt_pk_bf16_f32 %0, %1, %2" : "=v"(r) : "v"(f), "v"(f));
    return (short)r;
}

#define MFMA(a, b, c) __builtin_amdgcn_mfma_f32_16x16x32_bf16((a), (b), (c), 0, 0, 0)

// lgkmcnt-only barrier (proven r3): LDS ordering without draining vmcnt.
#define BARR() do { asm volatile("s_waitcnt lgkmcnt(0)" ::: "memory");            \
                    __builtin_amdgcn_s_barrier(); } while (0)

struct SM {
    alignas(16) short h1[2][16][KP];      // parity-buffered h1 (bf16), [n][k]
    alignas(16) short h2[2][16][KP];      // parity-buffered h2
    alignas(16) float part[2][16][4][8];  // out partials [parity][tile(pad16)][q][batch]
    alignas(16) float xstep[2][8][4];     // parity-chunked x staging [buf][batch][slot]
    float olds[8];
};

// A-frags (hi/lo split) for tile T of gate-stacked [3H][H] matrix, 4-padded rows:
// padded row 16T+n -> element j=4T+(n>>2), gate slot c=n&3.
// nslot selects which slot carries the n-gate row (2 = normal; 3 = moved, so a
// chained whh2+wih2 accumulator keeps n_h in .z and n_i in .w separately).
__device__ __forceinline__ void loadA(const float* __restrict__ src, int T, int n, int q,
                                      short8* ah, short8* al, int nslot) {
    const int jt = 4 * T + (n >> 2);
    const int c  = n & 3;
    const int g  = (c == 0) ? 0 : (c == 1) ? 1 : (c == nslot) ? 2 : -1;
    const bool rv = (g >= 0) && (jt < H);
#pragma unroll
    for (int kb = 0; kb < 2; ++kb) {
        short8 hi, lo;
#pragma unroll
        for (int jj = 0; jj < 8; ++jj) {
            const int k = kb * 32 + q * 8 + jj;
            const float v = (rv && k < H) ? src[(g * H + jt) * H + k] : 0.f;
            const unsigned short hb = f2bf(v);
            hi[jj] = (short)hb;
            lo[jj] = (short)f2bf(v - bf2f(hb));
        }
        ah[kb] = hi; al[kb] = lo;
    }
}

// chained 4-MFMA 2-term split matvec, bias/partial folded into accumulator init
__device__ __forceinline__ f32x4 dot4(const short8* ah, const short8* al,
                                      short8 b0, short8 b1, f32x4 init) {
    f32x4 acc = init;
    acc = MFMA(al[0], b0, acc);
    acc = MFMA(al[1], b1, acc);
    acc = MFMA(ah[0], b0, acc);
    acc = MFMA(ah[1], b1, acc);
    return acc;
}

__global__ __launch_bounds__(NT, 1) void gru_persist(
    const float* __restrict__ inp, const int* __restrict__ fut,
    const float* __restrict__ wih1, const float* __restrict__ whh1,
    const float* __restrict__ bih1, const float* __restrict__ bhh1,
    const float* __restrict__ wih2, const float* __restrict__ whh2,
    const float* __restrict__ bih2, const float* __restrict__ bhh2,
    const float* __restrict__ wlin, const float* __restrict__ blin,
    float* __restrict__ out)
{
    __shared__ SM sm;
    const int t = threadIdx.x, bg = blockIdx.x;
    const int w = t >> 6, lane = t & 63;
    const int n = lane & 15, q = lane >> 4;
    // SIMD balance: waves round-robin w%4 onto SIMDs. Tile 12 moved from wave
    // 12 to wave 15 so light waves {12,13,14,15} hit distinct SIMDs -> every
    // SIMD carries exactly 3 matvec waves + 1 light wave.
    const bool doM = (w < 12) || (w == 15);
    const int  T   = (w == 15) ? 12 : (doM ? w : 0);
    const int  j   = 4 * T + q;
    const bool jv  = doM && (j < H) && (n < NB);
    const int  jcl = (j < H) ? j : 0;

    // ---- A-fragments: 12 short8 = 48 VGPRs (wih2's n-row in slot 3) ----
    short8 a1h[2], a1l[2], a2h[2], a2l[2], a3h[2], a3l[2];
    loadA(whh1, T, n, q, a1h, a1l, 2);
    loadA(whh2, T, n, q, a2h, a2l, 2);
    loadA(wih2, T, n, q, a3h, a3l, 3);

    // ---- per-lane constants; biases folded into f32x4 accumulator inits ----
    // L1 chain: .x/.y = both r/z biases, .z = bhh1n (h-side), .w = bih1n (i-side,
    // preserved through the zero slot-3 row of whh1's A).
    const f32x4 b1v  = {bhh1[jcl] + bih1[jcl], bhh1[H + jcl] + bih1[H + jcl],
                        bhh1[2 * H + jcl], bih1[2 * H + jcl]};
    // L2 combined chain (whh2 then wih2): same structure.
    const f32x4 b2c2 = {bhh2[jcl] + bih2[jcl], bhh2[H + jcl] + bih2[H + jcl],
                        bhh2[2 * H + jcl], bih2[2 * H + jcl]};
    // future-loop split inits (phases separated by a barrier there)
    const f32x4 ib2v = {bhh2[jcl], bhh2[H + jcl], bhh2[2 * H + jcl], 0.f};
    const f32x4 ic2v = {bih2[jcl], bih2[H + jcl], 0.f, bih2[2 * H + jcl]};
    const float w1r = wih1[jcl], w1z = wih1[H + jcl], w1n = wih1[2 * H + jcl];
    const float wl  = wlin[jcl];
    const float blin_r = blin[0];

    // ---- LDS init ----
    for (int i = t; i < 2 * 16 * KP; i += NT) { ((short*)sm.h1)[i] = 0; ((short*)sm.h2)[i] = 0; }
    for (int i = t; i < 2 * 16 * 4 * 8; i += NT) ((float*)sm.part)[i] = 0.f;
    if (t < 8) sm.olds[t] = 0.f;

    // ---- x staging: wave 13, lanes 0..7; parity-chunked double buffer ----
    const bool doX = (w == 13) && (lane < 8);
    const int  bs  = lane;
    const float* xrow = inp + (size_t)(bg * NB + (doX ? bs : 0)) * TSEQ;
    float4 xnxt = make_float4(0.f, 0.f, 0.f, 0.f);
    if (doX) {
        *(float4*)&sm.xstep[0][bs][0] = *(const float4*)xrow;     // x[0..3]
        xnxt = *(const float4*)(xrow + 4);                        // x[4..7]
    }

    float h1o = 0.f, h2o = 0.f;     // per-lane f32 hidden (element j, batch n)
    const int TT = TSEQ + fut[0];
    float* outp = out + (size_t)(bg * NB) * (size_t)TT;
    __syncthreads();

// wave-14 full output reduction: 13x4 tile-q partials per batch; conflict-free
#define RED14(PBUF, TIDX, SAVEO)                                                  \
{                                                                                 \
    const float* pb = &sm.part[PBUF][0][0][0];                                    \
    float v = 0.f;                                                                \
    _Pragma("unroll")                                                             \
    for (int c = 0; c < 8; ++c) v += pb[64 * c + lane];                           \
    v += __shfl_xor(v, 8);                                                        \
    v += __shfl_xor(v, 16);                                                       \
    v += __shfl_xor(v, 32);                                                       \
    if (lane < 8) {                                                               \
        const float o_ = v + blin_r;                                              \
        if (SAVEO) sm.olds[lane] = o_;                                            \
        outp[(size_t)lane * TT + (TIDX)] = o_;                                    \
    }                                                                             \
}

#define STEP(IV, PAR, DOL2, DORED)                                                \
{                                                                                 \
    const int i_ = (IV);                                                          \
    if (doM) {                                                                    \
        const short8 b10 = *(const short8*)&sm.h1[PAR][n][q * 8];                 \
        const short8 b11 = *(const short8*)&sm.h1[PAR][n][32 + q * 8];            \
        if (DOL2) {                                                               \
            const short8 b20 = *(const short8*)&sm.h2[PAR][n][q * 8];             \
            const short8 b21 = *(const short8*)&sm.h2[PAR][n][32 + q * 8];        \
            f32x4 g = dot4(a2h, a2l, b20, b21, b2c2);                             \
            g = dot4(a3h, a3l, b10, b11, g);                                      \
            const float gr = sigm(g.x);                                           \
            const float gz = sigm(g.y);                                           \
            const float gn = tanh_(fmaf(gr, g.z, g.w));                           \
            const float hn = gn + gz * (h2o - gn);                                \
            h2o = hn;                                                             \
            if (jv) { sm.h2[(PAR) ^ 1][n][j] = f2bf_rn(hn);                       \
                      sm.part[PAR][T][q][n] = wl * hn; }                          \
        }                                                                         \
        {                                                                         \
            const float xv = sm.xstep[(i_ >> 2) & 1][n & 7][i_ & 3];              \
            const f32x4 a = dot4(a1h, a1l, b10, b11, b1v);                        \
            const float gr = sigm(fmaf(xv, w1r, a.x));                            \
            const float gz = sigm(fmaf(xv, w1z, a.y));                            \
            const float gn = tanh_(fmaf(gr, a.z, fmaf(xv, w1n, a.w)));            \
            const float hn = gn + gz * (h1o - gn);                                \
            h1o = hn;                                                             \
            if (jv) sm.h1[(PAR) ^ 1][n][j] = f2bf_rn(hn);                         \
        }                                                                         \
    } else if (w == 14) {                                                         \
        if (DORED) RED14((PAR) ^ 1, i_ - 2, false)                                \
    } else if (doX && (i_ & 3) == 3 && (i_ + 1) < TSEQ) {                         \
        *(float4*)&sm.xstep[((i_ + 1) >> 2) & 1][bs][0] = xnxt;                   \
        if (i_ + 8 < TSEQ) xnxt = *(const float4*)(xrow + i_ + 5);                \
    }                                                                             \
    BARR();                                                                       \
}

    // ========== MAIN LOOP: 1 barrier/step, parity-specialized unroll-2 ==========
    STEP(0, 0, false, false)
    STEP(1, 1, true,  false)
    for (int i = 2; i < TSEQ; i += 2) {
        STEP(i,     0, true, true)
        STEP(i + 1, 1, true, true)
    }

    // ========== EPILOGUE: h2(TSEQ-1), flush o(TSEQ-2) and o(TSEQ-1) ==========
    // state: h1(TSEQ-1) in h1[0], h2(TSEQ-2) in h2[0]; part[1] holds o(TSEQ-2) partials
    if (doM) {
        const short8 b10 = *(const short8*)&sm.h1[0][n][q * 8];
        const short8 b11 = *(const short8*)&sm.h1[0][n][32 + q * 8];
        const short8 b20 = *(const short8*)&sm.h2[0][n][q * 8];
        const short8 b21 = *(const short8*)&sm.h2[0][n][32 + q * 8];
        f32x4 g = dot4(a2h, a2l, b20, b21, b2c2);
        g = dot4(a3h, a3l, b10, b11, g);
        const float gr = sigm(g.x);
        const float gz = sigm(g.y);
        const float gn = tanh_(fmaf(gr, g.z, g.w));
        const float hn = gn + gz * (h2o - gn);
        h2o = hn;
        if (jv) { sm.h2[1][n][j] = f2bf_rn(hn); sm.part[0][T][q][n] = wl * hn; }
    } else if (w == 14) {
        RED14(1, TSEQ - 2, false)
    }
    BARR();
    if (w == 14) {
        RED14(0, TSEQ - 1, true)
    }
    BARR();

    // ========== FUTURE LOOP: serial feedback, 3 barriers/step ==========
    int fp1 = 0, fh2 = 1;    // h1(TSEQ-1) in h1[0], h2(TSEQ-1) in h2[1]
    for (int ts = TSEQ; ts < TT; ++ts) {
        float g2r, g2z, g2n;
        if (doM) {
            const short8 b10 = *(const short8*)&sm.h1[fp1][n][q * 8];
            const short8 b11 = *(const short8*)&sm.h1[fp1][n][32 + q * 8];
            const short8 b20 = *(const short8*)&sm.h2[fh2][n][q * 8];
            const short8 b21 = *(const short8*)&sm.h2[fh2][n][32 + q * 8];
            const float  xv  = sm.olds[n & 7];
            {
                const f32x4 g = dot4(a2h, a2l, b20, b21, ib2v);
                g2r = g.x; g2z = g.y; g2n = g.z;
            }
            {
                const f32x4 a = dot4(a1h, a1l, b10, b11, b1v);
                const float gr = sigm(fmaf(xv, w1r, a.x));
                const float gz = sigm(fmaf(xv, w1z, a.y));
                const float gn = tanh_(fmaf(gr, a.z, fmaf(xv, w1n, a.w)));
                const float hn = gn + gz * (h1o - gn);
                h1o = hn;
                if (jv) sm.h1[fp1 ^ 1][n][j] = f2bf_rn(hn);
            }
        }
        BARR();
        if (doM) {
            const short8 c0 = *(const short8*)&sm.h1[fp1 ^ 1][n][q * 8];
            const short8 c1 = *(const short8*)&sm.h1[fp1 ^ 1][n][32 + q * 8];
            const f32x4 gi = dot4(a3h, a3l, c0, c1, ic2v);   // n-part lands in .w
            const float gr = sigm(gi.x + g2r);
            const float gz = sigm(gi.y + g2z);
            const float gn = tanh_(fmaf(gr, g2n, gi.w));
            const float hn = gn + gz * (h2o - gn);
            h2o = hn;
            if (jv) { sm.h2[fh2 ^ 1][n][j] = f2bf_rn(hn); sm.part[0][T][q][n] = wl * hn; }
        }
        BARR();
        if (w == 14) {
            RED14(0, ts, true)
        }
        BARR();
        fp1 ^= 1; fh2 ^= 1;
    }
}

extern "C" void kernel_launch(void* const* d_in, const int* in_sizes, int n_in,
                              void* d_out, int out_size, void* d_ws, size_t ws_size,
                              hipStream_t stream) {
    (void)in_sizes; (void)n_in; (void)d_ws; (void)ws_size; (void)out_size;
    gru_persist<<<BB / NB, NT, 0, stream>>>(
        (const float*)d_in[0], (const int*)d_in[1],
        (const float*)d_in[2], (const float*)d_in[3], (const float*)d_in[4], (const float*)d_in[5],
        (const float*)d_in[6], (const float*)d_in[7], (const float*)d_in[8], (const float*)d_in[9],
        (const float*)d_in[10], (const float*)d_in[11],
        (float*)d_out);
}